// Round 8
// baseline (161.602 us; speedup 1.0000x reference)
//
#include <hip/hip_runtime.h>
#include <hip/hip_bf16.h>

typedef __attribute__((ext_vector_type(8))) short bf16x8;
typedef __attribute__((ext_vector_type(8))) unsigned short ushort8;
typedef __attribute__((ext_vector_type(4))) float f32x4;
typedef __attribute__((ext_vector_type(16))) float f32x16;

typedef const __attribute__((address_space(1))) void gvoid;
typedef __attribute__((address_space(3))) void svoid;

__device__ __forceinline__ unsigned short f2bf(float f) {
  union { float f; unsigned int u; } v; v.f = f;
  unsigned int u = v.u;
  unsigned int r = (u + 0x7fffu + ((u >> 16) & 1u)) >> 16;
  return (unsigned short)r;
}

// ---------------- fp32 -> bf16 cast (vectorized) ----------------
__global__ void cast_kernel(const float* __restrict__ in, unsigned short* __restrict__ out, int n4) {
  int i = blockIdx.x * 256 + threadIdx.x;
  if (i < n4) {
    const float4 v = reinterpret_cast<const float4*>(in)[i];
    ushort4 o;
    o.x = f2bf(v.x); o.y = f2bf(v.y); o.z = f2bf(v.z); o.w = f2bf(v.w);
    reinterpret_cast<ushort4*>(out)[i] = o;
  }
}

// ---------------- C[M][N] = A[M][K] * B[N][K]^T, bf16 in, fp32 acc ----------------
// cols < qcols get scaled by qscale in the epilogue (folds attn's 1/8 into q).
template<bool OUT_BF16>
__global__ __launch_bounds__(256) void gemm_bt(const unsigned short* __restrict__ A,
                                               const unsigned short* __restrict__ B,
                                               void* __restrict__ Cv,
                                               int M, int N, int K,
                                               float qscale, int qcols) {
  constexpr int BM = 128, BK = 32;
  __shared__ alignas(16) unsigned short As[BM * BK];
  __shared__ alignas(16) unsigned short Bs[BM * BK];
  const int tid = threadIdx.x;
  const int l  = tid & 63;
  const int w  = tid >> 6;
  const int wr = w >> 1, wc = w & 1;
  const int lr = l & 15, lg = l >> 4;
  const long tile_m = (long)blockIdx.x * BM;
  const long tile_n = (long)blockIdx.y * BM;

  const int c0 = tid, c1 = tid + 256;
  const unsigned short* pa0 = A + (tile_m + (c0 >> 2)) * (long)K + (c0 & 3) * 8;
  const unsigned short* pa1 = A + (tile_m + (c1 >> 2)) * (long)K + (c1 & 3) * 8;
  const unsigned short* pb0 = B + (tile_n + (c0 >> 2)) * (long)K + (c0 & 3) * 8;
  const unsigned short* pb1 = B + (tile_n + (c1 >> 2)) * (long)K + (c1 & 3) * 8;
  unsigned short* lA0 = As + (w * 64) * 8;
  unsigned short* lA1 = As + (256 + w * 64) * 8;
  unsigned short* lB0 = Bs + (w * 64) * 8;
  unsigned short* lB1 = Bs + (256 + w * 64) * 8;

  f32x4 acc[4][4] = {};

  for (int k0 = 0; k0 < K; k0 += BK) {
    __syncthreads();
    __builtin_amdgcn_global_load_lds((gvoid*)(pa0 + k0), (svoid*)lA0, 16, 0, 0);
    __builtin_amdgcn_global_load_lds((gvoid*)(pa1 + k0), (svoid*)lA1, 16, 0, 0);
    __builtin_amdgcn_global_load_lds((gvoid*)(pb0 + k0), (svoid*)lB0, 16, 0, 0);
    __builtin_amdgcn_global_load_lds((gvoid*)(pb1 + k0), (svoid*)lB1, 16, 0, 0);
    __syncthreads();
    bf16x8 af[4], bfr[4];
#pragma unroll
    for (int m = 0; m < 4; ++m)
      af[m] = *reinterpret_cast<const bf16x8*>(As + (wr * 64 + m * 16 + lr) * BK + lg * 8);
#pragma unroll
    for (int n = 0; n < 4; ++n)
      bfr[n] = *reinterpret_cast<const bf16x8*>(Bs + (wc * 64 + n * 16 + lr) * BK + lg * 8);
#pragma unroll
    for (int m = 0; m < 4; ++m)
#pragma unroll
      for (int n = 0; n < 4; ++n)
        acc[m][n] = __builtin_amdgcn_mfma_f32_16x16x32_bf16(af[m], bfr[n], acc[m][n], 0, 0, 0);
  }

#pragma unroll
  for (int m = 0; m < 4; ++m)
#pragma unroll
    for (int n = 0; n < 4; ++n)
#pragma unroll
      for (int r = 0; r < 4; ++r) {
        long row = tile_m + wr * 64 + m * 16 + lg * 4 + r;
        long col = tile_n + wc * 64 + n * 16 + lr;
        float sc = (col < qcols) ? qscale : 1.0f;
        if (OUT_BF16)
          reinterpret_cast<unsigned short*>(Cv)[row * N + col] = f2bf(acc[m][n][r] * sc);
        else
          reinterpret_cast<float*>(Cv)[row * N + col] = acc[m][n][r] * sc;
      }
}

// ---------------- causal flash attention: 2-way KV split per block ------------
// grid = 512 blocks x 512 threads (8 waves). Block i: half=i>>8, rr=i&255,
// bx=rr&15, bh=(rr>>4)|(half<<4), qtb=half?15-bx:bx (complementary pairing).
// Strip = 128 q-rows. Waves 0-3 (h2=0) process EVEN KV tiles, waves 4-7 (h2=1)
// ODD tiles; wave's q-rows = qtb*128 + (w&3)*32. Rounds J = nt/2 (nt=2qtb+2).
// Staging: thread parity p=tid>>8 stages tile 2j+p into Ks[p]/Vt[p] (256
// threads per tile — round-6 cost). End: merge the two (m,l,O) partials via a
// 32KB LDS fp32 buffer (reuses KV space), waves 0-3 write the output.
// Per-tile math identical to round 6: S^T = mfma_32x32x16(A=K,B=Q), in-lane
// softmax + one shfl_xor(32), P->A-frags via cvt_pk+permlane32_swap, defer-max.
__global__ __launch_bounds__(512, 4) void attn_kernel(const unsigned short* __restrict__ qkv,
                                                      unsigned short* __restrict__ o) {
  constexpr int E = 3072, T = 2048;
  __shared__ alignas(16) unsigned short KVbuf[4][64 * 64]; // [p]=K, [2+p]=Vt
  __shared__ float alBuf[8][32];
  __shared__ float mBufA[128], lBufA[128], mBufB[128], lBufB[128];
  const int tid = threadIdx.x;
  const int l = tid & 63, w = tid >> 6;
  const int hh = l >> 5;       // lane half
  const int lc = l & 31;       // lane col: q-row (softmax) / d-col (O)
  const int wq = w & 3;        // q-subtile within strip
  const int h2 = w >> 2;       // KV parity this wave computes (== tid>>8)
  const int id = blockIdx.x;
  const int half = id >> 8, rr2 = id & 255;
  const int bx = rr2 & 15;
  const int bh = (rr2 >> 4) | (half << 4);
  const int qtb = half ? (15 - bx) : bx;
  const int b = bh >> 4, hd = bh & 15;
  const unsigned short* Qb = qkv + (size_t)b * T * E + hd * 64;
  const unsigned short* Kb = Qb + 1024;
  const unsigned short* Vb = Qb + 2048;

  const int qrow0 = qtb * 128 + wq * 32;
  const int qg = qrow0 + lc;       // lane's q-row (global)
  const int nt = 2 * qtb + 2;
  const int J = nt >> 1;           // rounds (2 tiles per round)

  unsigned short* Ks = KVbuf[h2];
  unsigned short* Vt = KVbuf[2 + h2];

  // staging duty: 256 threads per parity; st = tid&255
  const int st = tid & 255;
  const int kr0 = st >> 3, js0 = st & 7;
  const int kr1 = kr0 + 32;
  // thread stages tile (2j + h2): base offset rows (2j+h2)*64
  const unsigned short* sK = Kb + (size_t)(h2 * 64 + kr0) * E + js0 * 8;
  const unsigned short* sV = Vb + (size_t)(h2 * 64 + kr0) * E + js0 * 8;
  const size_t roundStep = (size_t)128 * E;   // 2 tiles per round

  // Q fragments (B-operand): col=lc=q, k(d) = 16c + 8*hh + j
  bf16x8 aq[4];
#pragma unroll
  for (int c = 0; c < 4; ++c)
    aq[c] = *reinterpret_cast<const bf16x8*>(Qb + (size_t)qg * E + c * 16 + hh * 8);

  f32x16 accO0 = {}, accO1 = {};   // O[q][d]: frag0 d=lc, frag1 d=32+lc
  float mL = -1e30f, ls = 0.f;

  // prologue: round-0 tiles into regs
  ushort8 k0 = *reinterpret_cast<const ushort8*>(sK);
  ushort8 k1 = *reinterpret_cast<const ushort8*>(sK + 32 * E);
  ushort8 v0 = *reinterpret_cast<const ushort8*>(sV);
  ushort8 v1 = *reinterpret_cast<const ushort8*>(sV + 32 * E);

  const int ksl0 = (js0 ^ (kr0 & 7)) << 3;
  const int ksl1 = (js0 ^ (kr1 & 7)) << 3;

  for (int j = 0; j < J; ++j) {
    __syncthreads();   // all waves done reading previous round's buffers
    *reinterpret_cast<ushort8*>(Ks + kr0 * 64 + ksl0) = k0;
    *reinterpret_cast<ushort8*>(Ks + kr1 * 64 + ksl1) = k1;
#pragma unroll
    for (int e = 0; e < 8; ++e) {
      int d = js0 * 8 + e;
      int swz = (d ^ (d >> 3)) & 7;
      Vt[d * 64 + ((((kr0 >> 3) ^ swz) << 3) | (kr0 & 7))] = (unsigned short)v0[e];
      Vt[d * 64 + ((((kr1 >> 3) ^ swz) << 3) | (kr1 & 7))] = (unsigned short)v1[e];
    }
    __syncthreads();   // staging visible
    if (2 * j + 2 + h2 < nt) {   // prefetch next round's tile for this parity
      const unsigned short* nK = sK + (size_t)(j + 1) * roundStep;
      const unsigned short* nV = sV + (size_t)(j + 1) * roundStep;
      k0 = *reinterpret_cast<const ushort8*>(nK);
      k1 = *reinterpret_cast<const ushort8*>(nK + 32 * E);
      v0 = *reinterpret_cast<const ushort8*>(nV);
      v1 = *reinterpret_cast<const ushort8*>(nV + 32 * E);
    }

    const int t = 2 * j + h2;            // this wave's tile
    if (t * 64 > qrow0 + 31) continue;   // wave-uniform: fully masked

    // ---- S^T = K · Q^T : D[k][q], 2 frags (k 0..31, 32..63) ----
    f32x16 sT0 = {}, sT1 = {};
#pragma unroll
    for (int c = 0; c < 4; ++c) {
      int sl = ((2 * c + hh) ^ (lc & 7)) << 3;
      bf16x8 ak0 = *reinterpret_cast<const bf16x8*>(Ks + lc * 64 + sl);
      bf16x8 ak1 = *reinterpret_cast<const bf16x8*>(Ks + (32 + lc) * 64 + sl);
      sT0 = __builtin_amdgcn_mfma_f32_32x32x16_bf16(ak0, aq[c], sT0, 0, 0, 0);
      sT1 = __builtin_amdgcn_mfma_f32_32x32x16_bf16(ak1, aq[c], sT1, 0, 0, 0);
    }

    // ---- causal mask + row max (in-lane; k = t*64+32n+(r&3)+8*(r>>2)+4hh) ----
    const bool needMask = (t * 64 + 63) > qrow0;   // max_k vs wave's MIN q-row
    float pm = -1e30f;
#pragma unroll
    for (int r = 0; r < 16; ++r) {
      int kb = t * 64 + (r & 3) + 8 * (r >> 2) + 4 * hh;
      float a0 = sT0[r], a1 = sT1[r];
      if (needMask) {
        if (kb > qg) a0 = -1e30f;
        if (kb + 32 > qg) a1 = -1e30f;
      }
      sT0[r] = a0; sT1[r] = a1;
      pm = fmaxf(pm, fmaxf(a0, a1));
    }
    pm = fmaxf(pm, __shfl_xor(pm, 32));   // lane pair shares the q-row

    // ---- defer-max (THR=8): rescale O only when max grows materially ----
    if (__any(pm > mL + 8.f)) {
      float mn = fmaxf(mL, pm);
      float al = __expf(mL - mn);
      mL = mn;
      ls *= al;
      alBuf[w][lc] = al;
      asm volatile("s_waitcnt lgkmcnt(0)" ::: "memory");
      __builtin_amdgcn_sched_barrier(0);
#pragma unroll
      for (int r = 0; r < 16; ++r) {
        float alr = alBuf[w][(r & 3) + 8 * (r >> 2) + 4 * hh];
        accO0[r] *= alr;
        accO1[r] *= alr;
      }
    }

    // ---- P = exp(S-m); build PV A-frags in-register (cvt_pk + permlane32_swap) --
    bf16x8 pa[4];
    union U4 { unsigned int u[4]; bf16x8 v; };
#pragma unroll
    for (int n = 0; n < 2; ++n) {
      float p[16];
#pragma unroll
      for (int r = 0; r < 16; ++r) {
        float pv = __expf((n ? sT1[r] : sT0[r]) - mL);
        p[r] = pv;
        ls += pv;
      }
#pragma unroll
      for (int gg = 0; gg < 2; ++gg) {     // frag c' = 2n + gg, from p[8gg..8gg+7]
        unsigned int x0, x1, y0, y1;
        asm("v_cvt_pk_bf16_f32 %0, %1, %2" : "=v"(x0) : "v"(p[8 * gg + 0]), "v"(p[8 * gg + 1]));
        asm("v_cvt_pk_bf16_f32 %0, %1, %2" : "=v"(x1) : "v"(p[8 * gg + 2]), "v"(p[8 * gg + 3]));
        asm("v_cvt_pk_bf16_f32 %0, %1, %2" : "=v"(y0) : "v"(p[8 * gg + 4]), "v"(p[8 * gg + 5]));
        asm("v_cvt_pk_bf16_f32 %0, %1, %2" : "=v"(y1) : "v"(p[8 * gg + 6]), "v"(p[8 * gg + 7]));
        asm("v_permlane32_swap_b32 %0, %1" : "+v"(x0), "+v"(y0));
        asm("v_permlane32_swap_b32 %0, %1" : "+v"(x1), "+v"(y1));
        U4 fu;
        fu.u[0] = x0; fu.u[1] = x1; fu.u[2] = y0; fu.u[3] = y1;
        pa[2 * n + gg] = fu.v;
      }
    }

    // ---- O += P V : B[k][d] from Vt; frag m: d = 32m + lc ----
#pragma unroll
    for (int cp = 0; cp < 4; ++cp) {
      int d0 = lc, d1 = 32 + lc;
      int sl0 = ((2 * cp + hh) ^ ((d0 ^ (d0 >> 3)) & 7)) << 3;
      int sl1 = ((2 * cp + hh) ^ ((d1 ^ (d1 >> 3)) & 7)) << 3;
      bf16x8 bv0 = *reinterpret_cast<const bf16x8*>(Vt + d0 * 64 + sl0);
      bf16x8 bv1 = *reinterpret_cast<const bf16x8*>(Vt + d1 * 64 + sl1);
      accO0 = __builtin_amdgcn_mfma_f32_32x32x16_bf16(pa[cp], bv0, accO0, 0, 0, 0);
      accO1 = __builtin_amdgcn_mfma_f32_32x32x16_bf16(pa[cp], bv1, accO1, 0, 0, 0);
    }
  } // j

  // ---- combine the two KV-half partials, normalize, store ----
  __syncthreads();                       // all rounds done; KVbuf reusable
  float lsTot = ls + __shfl_xor(ls, 32);
  float* cb = (float*)KVbuf;             // 128 x 64 fp32 = 32 KB
  if (h2 == 1) {
    if (hh == 0) { mBufB[wq * 32 + lc] = mL; lBufB[wq * 32 + lc] = lsTot; }
#pragma unroll
    for (int r = 0; r < 16; ++r) {
      int q = (r & 3) + 8 * (r >> 2) + 4 * hh;
      int row = wq * 32 + q;
      cb[row * 64 + lc]      = accO0[r];
      cb[row * 64 + 32 + lc] = accO1[r];
    }
  } else {
    if (hh == 0) { mBufA[wq * 32 + lc] = mL; lBufA[wq * 32 + lc] = lsTot; }
  }
  __syncthreads();
  if (h2 == 0) {
#pragma unroll
    for (int r = 0; r < 16; ++r) {
      int q = (r & 3) + 8 * (r >> 2) + 4 * hh;
      int row = wq * 32 + q;
      float mA = mBufA[row], lA = lBufA[row];
      float mB = mBufB[row], lB = lBufB[row];
      float mS = fmaxf(mA, mB);
      float eA = __expf(mA - mS), eB = __expf(mB - mS);
      float inv = 1.f / (lA * eA + lB * eB);
      float o0 = (accO0[r] * eA + cb[row * 64 + lc] * eB) * inv;
      float o1 = (accO1[r] * eA + cb[row * 64 + 32 + lc] * eB) * inv;
      size_t orow = (size_t)(b * T + qtb * 128 + row) * 1024 + hd * 64;
      o[orow + lc]      = f2bf(o0);
      o[orow + 32 + lc] = f2bf(o1);
    }
  }
}

extern "C" void kernel_launch(void* const* d_in, const int* in_sizes, int n_in,
                              void* d_out, int out_size, void* d_ws, size_t ws_size,
                              hipStream_t stream) {
  const float* x     = (const float*)d_in[0];   // [2,2048,1024]
  const float* w_qkv = (const float*)d_in[1];   // [3072,1024]
  const float* w_out = (const float*)d_in[2];   // [1024,1024]
  float* out = (float*)d_out;                   // [2,2048,1024] fp32

  unsigned short* xb    = (unsigned short*)d_ws;                  // 4096*1024
  unsigned short* wqkvb = xb    + (size_t)4096 * 1024;            // 3072*1024
  unsigned short* woutb = wqkvb + (size_t)3072 * 1024;            // 1024*1024
  unsigned short* qkv   = woutb + (size_t)1024 * 1024;            // 4096*3072
  unsigned short* attn  = qkv   + (size_t)4096 * 3072;            // 4096*1024

  cast_kernel<<<dim3(4096), 256, 0, stream>>>(x,     xb,    4096 * 1024 / 4);
  cast_kernel<<<dim3(3072), 256, 0, stream>>>(w_qkv, wqkvb, 3072 * 1024 / 4);
  cast_kernel<<<dim3(1024), 256, 0, stream>>>(w_out, woutb, 1024 * 1024 / 4);

  gemm_bt<true ><<<dim3(32, 24), 256, 0, stream>>>(xb,   wqkvb, (void*)qkv,  4096, 3072, 1024,
                                                   0.125f, 1024);
  attn_kernel  <<<dim3(512), 512, 0, stream>>>(qkv, attn);
  gemm_bt<false><<<dim3(32,  8), 256, 0, stream>>>(attn, woutb, (void*)out, 4096, 1024, 1024,
                                                   1.0f, 0);
}

// Round 9
// 137.378 us; speedup vs baseline: 1.1763x; 1.1763x over previous
//
#include <hip/hip_runtime.h>
#include <hip/hip_bf16.h>

typedef __attribute__((ext_vector_type(8))) short bf16x8;
typedef __attribute__((ext_vector_type(8))) unsigned short ushort8;
typedef __attribute__((ext_vector_type(4))) float f32x4;
typedef __attribute__((ext_vector_type(16))) float f32x16;

typedef const __attribute__((address_space(1))) void gvoid;
typedef __attribute__((address_space(3))) void svoid;

__device__ __forceinline__ unsigned short f2bf(float f) {
  union { float f; unsigned int u; } v; v.f = f;
  unsigned int u = v.u;
  unsigned int r = (u + 0x7fffu + ((u >> 16) & 1u)) >> 16;
  return (unsigned short)r;
}

// ---------------- fp32 -> bf16 cast (vectorized) ----------------
__global__ void cast_kernel(const float* __restrict__ in, unsigned short* __restrict__ out, int n4) {
  int i = blockIdx.x * 256 + threadIdx.x;
  if (i < n4) {
    const float4 v = reinterpret_cast<const float4*>(in)[i];
    ushort4 o;
    o.x = f2bf(v.x); o.y = f2bf(v.y); o.z = f2bf(v.z); o.w = f2bf(v.w);
    reinterpret_cast<ushort4*>(out)[i] = o;
  }
}

// ---------------- C[M][N] = A[M][K] * B[N][K]^T, bf16 in, fp32 acc ----------------
// cols < qcols get scaled by qscale in the epilogue (folds attn's 1/8 into q).
template<bool OUT_BF16>
__global__ __launch_bounds__(256) void gemm_bt(const unsigned short* __restrict__ A,
                                               const unsigned short* __restrict__ B,
                                               void* __restrict__ Cv,
                                               int M, int N, int K,
                                               float qscale, int qcols) {
  constexpr int BM = 128, BK = 32;
  __shared__ alignas(16) unsigned short As[BM * BK];
  __shared__ alignas(16) unsigned short Bs[BM * BK];
  const int tid = threadIdx.x;
  const int l  = tid & 63;
  const int w  = tid >> 6;
  const int wr = w >> 1, wc = w & 1;
  const int lr = l & 15, lg = l >> 4;
  const long tile_m = (long)blockIdx.x * BM;
  const long tile_n = (long)blockIdx.y * BM;

  const int c0 = tid, c1 = tid + 256;
  const unsigned short* pa0 = A + (tile_m + (c0 >> 2)) * (long)K + (c0 & 3) * 8;
  const unsigned short* pa1 = A + (tile_m + (c1 >> 2)) * (long)K + (c1 & 3) * 8;
  const unsigned short* pb0 = B + (tile_n + (c0 >> 2)) * (long)K + (c0 & 3) * 8;
  const unsigned short* pb1 = B + (tile_n + (c1 >> 2)) * (long)K + (c1 & 3) * 8;
  unsigned short* lA0 = As + (w * 64) * 8;
  unsigned short* lA1 = As + (256 + w * 64) * 8;
  unsigned short* lB0 = Bs + (w * 64) * 8;
  unsigned short* lB1 = Bs + (256 + w * 64) * 8;

  f32x4 acc[4][4] = {};

  for (int k0 = 0; k0 < K; k0 += BK) {
    __syncthreads();
    __builtin_amdgcn_global_load_lds((gvoid*)(pa0 + k0), (svoid*)lA0, 16, 0, 0);
    __builtin_amdgcn_global_load_lds((gvoid*)(pa1 + k0), (svoid*)lA1, 16, 0, 0);
    __builtin_amdgcn_global_load_lds((gvoid*)(pb0 + k0), (svoid*)lB0, 16, 0, 0);
    __builtin_amdgcn_global_load_lds((gvoid*)(pb1 + k0), (svoid*)lB1, 16, 0, 0);
    __syncthreads();
    bf16x8 af[4], bfr[4];
#pragma unroll
    for (int m = 0; m < 4; ++m)
      af[m] = *reinterpret_cast<const bf16x8*>(As + (wr * 64 + m * 16 + lr) * BK + lg * 8);
#pragma unroll
    for (int n = 0; n < 4; ++n)
      bfr[n] = *reinterpret_cast<const bf16x8*>(Bs + (wc * 64 + n * 16 + lr) * BK + lg * 8);
#pragma unroll
    for (int m = 0; m < 4; ++m)
#pragma unroll
      for (int n = 0; n < 4; ++n)
        acc[m][n] = __builtin_amdgcn_mfma_f32_16x16x32_bf16(af[m], bfr[n], acc[m][n], 0, 0, 0);
  }

#pragma unroll
  for (int m = 0; m < 4; ++m)
#pragma unroll
    for (int n = 0; n < 4; ++n)
#pragma unroll
      for (int r = 0; r < 4; ++r) {
        long row = tile_m + wr * 64 + m * 16 + lg * 4 + r;
        long col = tile_n + wc * 64 + n * 16 + lr;
        float sc = (col < qcols) ? qscale : 1.0f;
        if (OUT_BF16)
          reinterpret_cast<unsigned short*>(Cv)[row * N + col] = f2bf(acc[m][n][r] * sc);
        else
          reinterpret_cast<float*>(Cv)[row * N + col] = acc[m][n][r] * sc;
      }
}

// ---------------- causal flash attention: 2-way KV split per block ------------
// grid = 512 blocks x 512 threads (8 waves). Block i: half=i>>8, rr=i&255,
// bx=rr&15, bh=(rr>>4)|(half<<4), qtb=half?15-bx:bx (complementary pairing).
// Strip = 128 q-rows. Waves 0-3 (h2=0) process EVEN KV tiles, waves 4-7 (h2=1)
// ODD tiles; wave's q-rows = qtb*128 + (w&3)*32. Rounds J = nt/2 (nt=2qtb+2).
// Staging: thread parity p=tid>>8 stages tile 2j+p into Ks[p]/Vt[p] (256
// threads per tile). End: merge the two (m,l,O) partials via a 32KB LDS fp32
// buffer (reuses KV space), waves 0-3 write the output.
// ROUND-9 FIX: __launch_bounds__(512, 2) — round 8's (512,4) demanded 4
// waves/SIMD, capping VGPR at 64 -> f32x16 accumulators spilled to scratch
// (WRITE_SIZE 44MB, FETCH +40MB). (512,2) caps at 256 VGPR: no spill,
// 2 blocks/CU by VGPR (LDS 35.8KB would allow 4).
__global__ __launch_bounds__(512, 2) void attn_kernel(const unsigned short* __restrict__ qkv,
                                                      unsigned short* __restrict__ o) {
  constexpr int E = 3072, T = 2048;
  __shared__ alignas(16) unsigned short KVbuf[4][64 * 64]; // [p]=K, [2+p]=Vt
  __shared__ float alBuf[8][32];
  __shared__ float mBufA[128], lBufA[128], mBufB[128], lBufB[128];
  const int tid = threadIdx.x;
  const int l = tid & 63, w = tid >> 6;
  const int hh = l >> 5;       // lane half
  const int lc = l & 31;       // lane col: q-row (softmax) / d-col (O)
  const int wq = w & 3;        // q-subtile within strip
  const int h2 = w >> 2;       // KV parity this wave computes (== tid>>8)
  const int id = blockIdx.x;
  const int half = id >> 8, rr2 = id & 255;
  const int bx = rr2 & 15;
  const int bh = (rr2 >> 4) | (half << 4);
  const int qtb = half ? (15 - bx) : bx;
  const int b = bh >> 4, hd = bh & 15;
  const unsigned short* Qb = qkv + (size_t)b * T * E + hd * 64;
  const unsigned short* Kb = Qb + 1024;
  const unsigned short* Vb = Qb + 2048;

  const int qrow0 = qtb * 128 + wq * 32;
  const int qg = qrow0 + lc;       // lane's q-row (global)
  const int nt = 2 * qtb + 2;
  const int J = nt >> 1;           // rounds (2 tiles per round)

  unsigned short* Ks = KVbuf[h2];
  unsigned short* Vt = KVbuf[2 + h2];

  // staging duty: 256 threads per parity; st = tid&255
  const int st = tid & 255;
  const int kr0 = st >> 3, js0 = st & 7;
  const int kr1 = kr0 + 32;
  // thread stages tile (2j + h2): base offset rows (2j+h2)*64
  const unsigned short* sK = Kb + (size_t)(h2 * 64 + kr0) * E + js0 * 8;
  const unsigned short* sV = Vb + (size_t)(h2 * 64 + kr0) * E + js0 * 8;
  const size_t roundStep = (size_t)128 * E;   // 2 tiles per round

  // Q fragments (B-operand): col=lc=q, k(d) = 16c + 8*hh + j
  bf16x8 aq[4];
#pragma unroll
  for (int c = 0; c < 4; ++c)
    aq[c] = *reinterpret_cast<const bf16x8*>(Qb + (size_t)qg * E + c * 16 + hh * 8);

  f32x16 accO0 = {}, accO1 = {};   // O[q][d]: frag0 d=lc, frag1 d=32+lc
  float mL = -1e30f, ls = 0.f;

  // prologue: round-0 tiles into regs
  ushort8 k0 = *reinterpret_cast<const ushort8*>(sK);
  ushort8 k1 = *reinterpret_cast<const ushort8*>(sK + 32 * E);
  ushort8 v0 = *reinterpret_cast<const ushort8*>(sV);
  ushort8 v1 = *reinterpret_cast<const ushort8*>(sV + 32 * E);

  const int ksl0 = (js0 ^ (kr0 & 7)) << 3;
  const int ksl1 = (js0 ^ (kr1 & 7)) << 3;

  for (int j = 0; j < J; ++j) {
    __syncthreads();   // all waves done reading previous round's buffers
    *reinterpret_cast<ushort8*>(Ks + kr0 * 64 + ksl0) = k0;
    *reinterpret_cast<ushort8*>(Ks + kr1 * 64 + ksl1) = k1;
#pragma unroll
    for (int e = 0; e < 8; ++e) {
      int d = js0 * 8 + e;
      int swz = (d ^ (d >> 3)) & 7;
      Vt[d * 64 + ((((kr0 >> 3) ^ swz) << 3) | (kr0 & 7))] = (unsigned short)v0[e];
      Vt[d * 64 + ((((kr1 >> 3) ^ swz) << 3) | (kr1 & 7))] = (unsigned short)v1[e];
    }
    __syncthreads();   // staging visible
    if (2 * j + 2 + h2 < nt) {   // prefetch next round's tile for this parity
      const unsigned short* nK = sK + (size_t)(j + 1) * roundStep;
      const unsigned short* nV = sV + (size_t)(j + 1) * roundStep;
      k0 = *reinterpret_cast<const ushort8*>(nK);
      k1 = *reinterpret_cast<const ushort8*>(nK + 32 * E);
      v0 = *reinterpret_cast<const ushort8*>(nV);
      v1 = *reinterpret_cast<const ushort8*>(nV + 32 * E);
    }

    const int t = 2 * j + h2;            // this wave's tile
    if (t * 64 > qrow0 + 31) continue;   // wave-uniform: fully masked

    // ---- S^T = K · Q^T : D[k][q], 2 frags (k 0..31, 32..63) ----
    f32x16 sT0 = {}, sT1 = {};
#pragma unroll
    for (int c = 0; c < 4; ++c) {
      int sl = ((2 * c + hh) ^ (lc & 7)) << 3;
      bf16x8 ak0 = *reinterpret_cast<const bf16x8*>(Ks + lc * 64 + sl);
      bf16x8 ak1 = *reinterpret_cast<const bf16x8*>(Ks + (32 + lc) * 64 + sl);
      sT0 = __builtin_amdgcn_mfma_f32_32x32x16_bf16(ak0, aq[c], sT0, 0, 0, 0);
      sT1 = __builtin_amdgcn_mfma_f32_32x32x16_bf16(ak1, aq[c], sT1, 0, 0, 0);
    }

    // ---- causal mask + row max (in-lane; k = t*64+32n+(r&3)+8*(r>>2)+4hh) ----
    const bool needMask = (t * 64 + 63) > qrow0;   // max_k vs wave's MIN q-row
    float pm = -1e30f;
#pragma unroll
    for (int r = 0; r < 16; ++r) {
      int kb = t * 64 + (r & 3) + 8 * (r >> 2) + 4 * hh;
      float a0 = sT0[r], a1 = sT1[r];
      if (needMask) {
        if (kb > qg) a0 = -1e30f;
        if (kb + 32 > qg) a1 = -1e30f;
      }
      sT0[r] = a0; sT1[r] = a1;
      pm = fmaxf(pm, fmaxf(a0, a1));
    }
    pm = fmaxf(pm, __shfl_xor(pm, 32));   // lane pair shares the q-row

    // ---- defer-max (THR=8): rescale O only when max grows materially ----
    if (__any(pm > mL + 8.f)) {
      float mn = fmaxf(mL, pm);
      float al = __expf(mL - mn);
      mL = mn;
      ls *= al;
      alBuf[w][lc] = al;
      asm volatile("s_waitcnt lgkmcnt(0)" ::: "memory");
      __builtin_amdgcn_sched_barrier(0);
#pragma unroll
      for (int r = 0; r < 16; ++r) {
        float alr = alBuf[w][(r & 3) + 8 * (r >> 2) + 4 * hh];
        accO0[r] *= alr;
        accO1[r] *= alr;
      }
    }

    // ---- P = exp(S-m); build PV A-frags in-register (cvt_pk + permlane32_swap) --
    bf16x8 pa[4];
    union U4 { unsigned int u[4]; bf16x8 v; };
#pragma unroll
    for (int n = 0; n < 2; ++n) {
      float p[16];
#pragma unroll
      for (int r = 0; r < 16; ++r) {
        float pv = __expf((n ? sT1[r] : sT0[r]) - mL);
        p[r] = pv;
        ls += pv;
      }
#pragma unroll
      for (int gg = 0; gg < 2; ++gg) {     // frag c' = 2n + gg, from p[8gg..8gg+7]
        unsigned int x0, x1, y0, y1;
        asm("v_cvt_pk_bf16_f32 %0, %1, %2" : "=v"(x0) : "v"(p[8 * gg + 0]), "v"(p[8 * gg + 1]));
        asm("v_cvt_pk_bf16_f32 %0, %1, %2" : "=v"(x1) : "v"(p[8 * gg + 2]), "v"(p[8 * gg + 3]));
        asm("v_cvt_pk_bf16_f32 %0, %1, %2" : "=v"(y0) : "v"(p[8 * gg + 4]), "v"(p[8 * gg + 5]));
        asm("v_cvt_pk_bf16_f32 %0, %1, %2" : "=v"(y1) : "v"(p[8 * gg + 6]), "v"(p[8 * gg + 7]));
        asm("v_permlane32_swap_b32 %0, %1" : "+v"(x0), "+v"(y0));
        asm("v_permlane32_swap_b32 %0, %1" : "+v"(x1), "+v"(y1));
        U4 fu;
        fu.u[0] = x0; fu.u[1] = x1; fu.u[2] = y0; fu.u[3] = y1;
        pa[2 * n + gg] = fu.v;
      }
    }

    // ---- O += P V : B[k][d] from Vt; frag m: d = 32m + lc ----
#pragma unroll
    for (int cp = 0; cp < 4; ++cp) {
      int d0 = lc, d1 = 32 + lc;
      int sl0 = ((2 * cp + hh) ^ ((d0 ^ (d0 >> 3)) & 7)) << 3;
      int sl1 = ((2 * cp + hh) ^ ((d1 ^ (d1 >> 3)) & 7)) << 3;
      bf16x8 bv0 = *reinterpret_cast<const bf16x8*>(Vt + d0 * 64 + sl0);
      bf16x8 bv1 = *reinterpret_cast<const bf16x8*>(Vt + d1 * 64 + sl1);
      accO0 = __builtin_amdgcn_mfma_f32_32x32x16_bf16(pa[cp], bv0, accO0, 0, 0, 0);
      accO1 = __builtin_amdgcn_mfma_f32_32x32x16_bf16(pa[cp], bv1, accO1, 0, 0, 0);
    }
  } // j

  // ---- combine the two KV-half partials, normalize, store ----
  __syncthreads();                       // all rounds done; KVbuf reusable
  float lsTot = ls + __shfl_xor(ls, 32);
  float* cb = (float*)KVbuf;             // 128 x 64 fp32 = 32 KB
  if (h2 == 1) {
    if (hh == 0) { mBufB[wq * 32 + lc] = mL; lBufB[wq * 32 + lc] = lsTot; }
#pragma unroll
    for (int r = 0; r < 16; ++r) {
      int q = (r & 3) + 8 * (r >> 2) + 4 * hh;
      int row = wq * 32 + q;
      cb[row * 64 + lc]      = accO0[r];
      cb[row * 64 + 32 + lc] = accO1[r];
    }
  } else {
    if (hh == 0) { mBufA[wq * 32 + lc] = mL; lBufA[wq * 32 + lc] = lsTot; }
  }
  __syncthreads();
  if (h2 == 0) {
#pragma unroll
    for (int r = 0; r < 16; ++r) {
      int q = (r & 3) + 8 * (r >> 2) + 4 * hh;
      int row = wq * 32 + q;
      float mA = mBufA[row], lA = lBufA[row];
      float mB = mBufB[row], lB = lBufB[row];
      float mS = fmaxf(mA, mB);
      float eA = __expf(mA - mS), eB = __expf(mB - mS);
      float inv = 1.f / (lA * eA + lB * eB);
      float o0 = (accO0[r] * eA + cb[row * 64 + lc] * eB) * inv;
      float o1 = (accO1[r] * eA + cb[row * 64 + 32 + lc] * eB) * inv;
      size_t orow = (size_t)(b * T + qtb * 128 + row) * 1024 + hd * 64;
      o[orow + lc]      = f2bf(o0);
      o[orow + 32 + lc] = f2bf(o1);
    }
  }
}

extern "C" void kernel_launch(void* const* d_in, const int* in_sizes, int n_in,
                              void* d_out, int out_size, void* d_ws, size_t ws_size,
                              hipStream_t stream) {
  const float* x     = (const float*)d_in[0];   // [2,2048,1024]
  const float* w_qkv = (const float*)d_in[1];   // [3072,1024]
  const float* w_out = (const float*)d_in[2];   // [1024,1024]
  float* out = (float*)d_out;                   // [2,2048,1024] fp32

  unsigned short* xb    = (unsigned short*)d_ws;                  // 4096*1024
  unsigned short* wqkvb = xb    + (size_t)4096 * 1024;            // 3072*1024
  unsigned short* woutb = wqkvb + (size_t)3072 * 1024;            // 1024*1024
  unsigned short* qkv   = woutb + (size_t)1024 * 1024;            // 4096*3072
  unsigned short* attn  = qkv   + (size_t)4096 * 3072;            // 4096*1024

  cast_kernel<<<dim3(4096), 256, 0, stream>>>(x,     xb,    4096 * 1024 / 4);
  cast_kernel<<<dim3(3072), 256, 0, stream>>>(w_qkv, wqkvb, 3072 * 1024 / 4);
  cast_kernel<<<dim3(1024), 256, 0, stream>>>(w_out, woutb, 1024 * 1024 / 4);

  gemm_bt<true ><<<dim3(32, 24), 256, 0, stream>>>(xb,   wqkvb, (void*)qkv,  4096, 3072, 1024,
                                                   0.125f, 1024);
  attn_kernel  <<<dim3(512), 512, 0, stream>>>(qkv, attn);
  gemm_bt<false><<<dim3(32,  8), 256, 0, stream>>>(attn, woutb, (void*)out, 4096, 1024, 1024,
                                                   1.0f, 0);
}

// Round 10
// 116.750 us; speedup vs baseline: 1.3842x; 1.1767x over previous
//
#include <hip/hip_runtime.h>
#include <hip/hip_bf16.h>

typedef __attribute__((ext_vector_type(8))) short bf16x8;
typedef __attribute__((ext_vector_type(8))) unsigned short ushort8;
typedef __attribute__((ext_vector_type(4))) float f32x4;
typedef __attribute__((ext_vector_type(16))) float f32x16;

typedef const __attribute__((address_space(1))) void gvoid;
typedef __attribute__((address_space(3))) void svoid;

__device__ __forceinline__ unsigned short f2bf(float f) {
  union { float f; unsigned int u; } v; v.f = f;
  unsigned int u = v.u;
  unsigned int r = (u + 0x7fffu + ((u >> 16) & 1u)) >> 16;
  return (unsigned short)r;
}

// ---------------- fused fp32 -> bf16 cast for all three inputs ----------------
__global__ void cast3_kernel(const float* __restrict__ a, int na4,
                             const float* __restrict__ b, int nb4,
                             const float* __restrict__ c, int nc4,
                             unsigned short* __restrict__ oa,
                             unsigned short* __restrict__ ob,
                             unsigned short* __restrict__ oc) {
  const int total = na4 + nb4 + nc4;
  for (int i = blockIdx.x * 256 + threadIdx.x; i < total; i += gridDim.x * 256) {
    const float* src; unsigned short* dst; int j = i;
    if (j < na4) { src = a; dst = oa; }
    else if (j < na4 + nb4) { j -= na4; src = b; dst = ob; }
    else { j -= na4 + nb4; src = c; dst = oc; }
    const float4 v = reinterpret_cast<const float4*>(src)[j];
    ushort4 o4;
    o4.x = f2bf(v.x); o4.y = f2bf(v.y); o4.z = f2bf(v.z); o4.w = f2bf(v.w);
    reinterpret_cast<ushort4*>(dst)[j] = o4;
  }
}

// ---------------- C[M][N] = A[M][K] * B[N][K]^T, bf16 in, fp32 acc ----------------
// 2-phase double-buffered: stage tile k+1 (global_load_lds w=16) BEFORE computing
// tile k; ONE barrier per K-step (loads fly across the compute phase).
// cols < qcols get scaled by qscale in the epilogue (folds attn's 1/8 into q).
template<bool OUT_BF16>
__global__ __launch_bounds__(256) void gemm_bt(const unsigned short* __restrict__ A,
                                               const unsigned short* __restrict__ B,
                                               void* __restrict__ Cv,
                                               int M, int N, int K,
                                               float qscale, int qcols) {
  constexpr int BM = 128, BK = 32, TILE = BM * BK;
  __shared__ alignas(16) unsigned short As[2 * TILE];
  __shared__ alignas(16) unsigned short Bs[2 * TILE];
  const int tid = threadIdx.x;
  const int l  = tid & 63;
  const int w  = tid >> 6;
  const int wr = w >> 1, wc = w & 1;
  const int lr = l & 15, lg = l >> 4;
  const long tile_m = (long)blockIdx.x * BM;
  const long tile_n = (long)blockIdx.y * BM;

  const int c0 = tid, c1 = tid + 256;   // 16B-chunk ids; row = c>>2, col8 = (c&3)*8
  const unsigned short* pa0 = A + (tile_m + (c0 >> 2)) * (long)K + (c0 & 3) * 8;
  const unsigned short* pa1 = A + (tile_m + (c1 >> 2)) * (long)K + (c1 & 3) * 8;
  const unsigned short* pb0 = B + (tile_n + (c0 >> 2)) * (long)K + (c0 & 3) * 8;
  const unsigned short* pb1 = B + (tile_n + (c1 >> 2)) * (long)K + (c1 & 3) * 8;
  const int woff = w * 512;   // wave-uniform LDS chunk base (lane adds *16B)

  f32x4 acc[4][4] = {};

  // prologue: stage tile 0 into buffer 0
  __builtin_amdgcn_global_load_lds((gvoid*)pa0, (svoid*)(As + woff), 16, 0, 0);
  __builtin_amdgcn_global_load_lds((gvoid*)pa1, (svoid*)(As + 2048 + woff), 16, 0, 0);
  __builtin_amdgcn_global_load_lds((gvoid*)pb0, (svoid*)(Bs + woff), 16, 0, 0);
  __builtin_amdgcn_global_load_lds((gvoid*)pb1, (svoid*)(Bs + 2048 + woff), 16, 0, 0);
  __syncthreads();

  int cur = 0;
  for (int k0 = 0; k0 < K; k0 += BK) {
    if (k0 + BK < K) {   // stage next tile into back buffer (overlaps compute)
      unsigned short* An = As + (cur ^ 1) * TILE;
      unsigned short* Bn = Bs + (cur ^ 1) * TILE;
      __builtin_amdgcn_global_load_lds((gvoid*)(pa0 + k0 + BK), (svoid*)(An + woff), 16, 0, 0);
      __builtin_amdgcn_global_load_lds((gvoid*)(pa1 + k0 + BK), (svoid*)(An + 2048 + woff), 16, 0, 0);
      __builtin_amdgcn_global_load_lds((gvoid*)(pb0 + k0 + BK), (svoid*)(Bn + woff), 16, 0, 0);
      __builtin_amdgcn_global_load_lds((gvoid*)(pb1 + k0 + BK), (svoid*)(Bn + 2048 + woff), 16, 0, 0);
    }
    const unsigned short* AsC = As + cur * TILE;
    const unsigned short* BsC = Bs + cur * TILE;
    bf16x8 af[4], bfr[4];
#pragma unroll
    for (int m = 0; m < 4; ++m)
      af[m] = *reinterpret_cast<const bf16x8*>(AsC + (wr * 64 + m * 16 + lr) * BK + lg * 8);
#pragma unroll
    for (int n = 0; n < 4; ++n)
      bfr[n] = *reinterpret_cast<const bf16x8*>(BsC + (wc * 64 + n * 16 + lr) * BK + lg * 8);
#pragma unroll
    for (int m = 0; m < 4; ++m)
#pragma unroll
      for (int n = 0; n < 4; ++n)
        acc[m][n] = __builtin_amdgcn_mfma_f32_16x16x32_bf16(af[m], bfr[n], acc[m][n], 0, 0, 0);
    __syncthreads();   // staged back-buffer complete + all reads of cur done
    cur ^= 1;
  }

#pragma unroll
  for (int m = 0; m < 4; ++m)
#pragma unroll
    for (int n = 0; n < 4; ++n)
#pragma unroll
      for (int r = 0; r < 4; ++r) {
        long row = tile_m + wr * 64 + m * 16 + lg * 4 + r;
        long col = tile_n + wc * 64 + n * 16 + lr;
        float sc = (col < qcols) ? qscale : 1.0f;
        if (OUT_BF16)
          reinterpret_cast<unsigned short*>(Cv)[row * N + col] = f2bf(acc[m][n][r] * sc);
        else
          reinterpret_cast<float*>(Cv)[row * N + col] = acc[m][n][r] * sc;
      }
}

// ---------------- causal flash attention (round-6 proven: 57 µs) --------------
// grid = 512 blocks x 256 threads (4 waves). Block i: half=i>>8, bx=i&15,
// bh=(i>>4)&15 | half<<4, qtb = half?15-bx:bx (complementary causal pairing).
// Wave w owns 32 q-rows [qtb*128 + w*32, +32). Per KV tile (64 k):
//   S^T = mfma_32x32x16(A=K, B=Q): lane holds 32 S-values, ALL for q-row
//   (lane&31); k = n*32 + (r&3)+8*(r>>2)+4*(lane>>5). Row-softmax is in-lane
//   + ONE shfl_xor(32). P->A-frags via v_cvt_pk_bf16_f32 + v_permlane32_swap.
//   Defer-max (THR=8) LDS broadcast of rescale factors. Q pre-scaled 0.125.
__global__ __launch_bounds__(256, 2) void attn_kernel(const unsigned short* __restrict__ qkv,
                                                      unsigned short* __restrict__ o) {
  constexpr int E = 3072, T = 2048;
  __shared__ alignas(16) unsigned short Ks[64 * 64];   // [k][d], slot ^= k&7
  __shared__ alignas(16) unsigned short Vt[64 * 64];   // [d][k], slot ^= (d^(d>>3))&7
  __shared__ float alBuf[4][32];
  const int tid = threadIdx.x;
  const int l = tid & 63, w = tid >> 6;
  const int hh = l >> 5;       // lane half
  const int lc = l & 31;       // lane col: q-row (softmax) / d-col (O)
  const int id = blockIdx.x;
  const int half = id >> 8, rr2 = id & 255;
  const int bx = rr2 & 15;
  const int bh = (rr2 >> 4) | (half << 4);
  const int qtb = half ? (15 - bx) : bx;
  const int b = bh >> 4, hd = bh & 15;
  const unsigned short* Qb = qkv + (size_t)b * T * E + hd * 64;
  const unsigned short* Kb = Qb + 1024;
  const unsigned short* Vb = Qb + 2048;

  const int qrow0 = qtb * 128 + w * 32;
  const int qg = qrow0 + lc;       // lane's q-row (global)
  const int nt = 2 * qtb + 2;

  // staging duty: 256 threads, 2 chunks each (rows 0..31 and 32..63)
  const int kr0 = tid >> 3, js0 = tid & 7;
  const int kr1 = kr0 + 32;
  const unsigned short* sK = Kb + (size_t)kr0 * E + js0 * 8;
  const unsigned short* sV = Vb + (size_t)kr0 * E + js0 * 8;
  const size_t tileStep = (size_t)64 * E;

  // Q fragments (B-operand): col=lc=q, k(d) = 16c + 8*hh + j
  bf16x8 aq[4];
#pragma unroll
  for (int c = 0; c < 4; ++c)
    aq[c] = *reinterpret_cast<const bf16x8*>(Qb + (size_t)qg * E + c * 16 + hh * 8);

  f32x16 accO0 = {}, accO1 = {};   // O[q][d]: frag0 d=lc, frag1 d=32+lc
  float mL = -1e30f, ls = 0.f;

  // prologue: tile 0 into regs
  ushort8 k0 = *reinterpret_cast<const ushort8*>(sK);
  ushort8 k1 = *reinterpret_cast<const ushort8*>(sK + 32 * E);
  ushort8 v0 = *reinterpret_cast<const ushort8*>(sV);
  ushort8 v1 = *reinterpret_cast<const ushort8*>(sV + 32 * E);

  for (int t = 0; t < nt; ++t) {
    __syncthreads();   // all waves done reading previous tile
    *reinterpret_cast<ushort8*>(Ks + kr0 * 64 + ((js0 ^ (kr0 & 7)) << 3)) = k0;
    *reinterpret_cast<ushort8*>(Ks + kr1 * 64 + ((js0 ^ (kr1 & 7)) << 3)) = k1;
#pragma unroll
    for (int e = 0; e < 8; ++e) {
      int d = js0 * 8 + e;
      int swz = (d ^ (d >> 3)) & 7;
      Vt[d * 64 + ((((kr0 >> 3) ^ swz) << 3) | (kr0 & 7))] = (unsigned short)v0[e];
      Vt[d * 64 + ((((kr1 >> 3) ^ swz) << 3) | (kr1 & 7))] = (unsigned short)v1[e];
    }
    __syncthreads();   // staging visible
    if (t + 1 < nt) {  // prefetch next tile into regs (lands during compute)
      const unsigned short* nK = sK + (size_t)(t + 1) * tileStep;
      const unsigned short* nV = sV + (size_t)(t + 1) * tileStep;
      k0 = *reinterpret_cast<const ushort8*>(nK);
      k1 = *reinterpret_cast<const ushort8*>(nK + 32 * E);
      v0 = *reinterpret_cast<const ushort8*>(nV);
      v1 = *reinterpret_cast<const ushort8*>(nV + 32 * E);
    }

    if (t * 64 > qrow0 + 31) continue;   // wave-uniform: tile fully masked

    // ---- S^T = K · Q^T : D[k][q], 2 frags (k 0..31, 32..63) ----
    f32x16 sT0 = {}, sT1 = {};
#pragma unroll
    for (int c = 0; c < 4; ++c) {
      int sl = ((2 * c + hh) ^ (lc & 7)) << 3;
      bf16x8 ak0 = *reinterpret_cast<const bf16x8*>(Ks + lc * 64 + sl);
      bf16x8 ak1 = *reinterpret_cast<const bf16x8*>(Ks + (32 + lc) * 64 + sl);
      sT0 = __builtin_amdgcn_mfma_f32_32x32x16_bf16(ak0, aq[c], sT0, 0, 0, 0);
      sT1 = __builtin_amdgcn_mfma_f32_32x32x16_bf16(ak1, aq[c], sT1, 0, 0, 0);
    }

    // ---- causal mask + row max (in-lane; k = t*64+32n+(r&3)+8*(r>>2)+4hh) ----
    const bool needMask = (t * 64 + 63) > qrow0;   // max_k vs wave's MIN q-row
    float pm = -1e30f;
#pragma unroll
    for (int r = 0; r < 16; ++r) {
      int kb = t * 64 + (r & 3) + 8 * (r >> 2) + 4 * hh;
      float a0 = sT0[r], a1 = sT1[r];
      if (needMask) {
        if (kb > qg) a0 = -1e30f;
        if (kb + 32 > qg) a1 = -1e30f;
      }
      sT0[r] = a0; sT1[r] = a1;
      pm = fmaxf(pm, fmaxf(a0, a1));
    }
    pm = fmaxf(pm, __shfl_xor(pm, 32));   // lane pair shares the q-row

    // ---- defer-max (THR=8): rescale O only when max grows materially ----
    if (__any(pm > mL + 8.f)) {
      float mn = fmaxf(mL, pm);
      float al = __expf(mL - mn);
      mL = mn;
      ls *= al;
      alBuf[w][lc] = al;
      asm volatile("s_waitcnt lgkmcnt(0)" ::: "memory");
      __builtin_amdgcn_sched_barrier(0);
#pragma unroll
      for (int r = 0; r < 16; ++r) {
        float alr = alBuf[w][(r & 3) + 8 * (r >> 2) + 4 * hh];
        accO0[r] *= alr;
        accO1[r] *= alr;
      }
    }

    // ---- P = exp(S-m); build PV A-frags in-register (cvt_pk + permlane32_swap) --
    bf16x8 pa[4];
    union U4 { unsigned int u[4]; bf16x8 v; };
#pragma unroll
    for (int n = 0; n < 2; ++n) {
      float p[16];
#pragma unroll
      for (int r = 0; r < 16; ++r) {
        float pv = __expf((n ? sT1[r] : sT0[r]) - mL);
        p[r] = pv;
        ls += pv;
      }
#pragma unroll
      for (int gg = 0; gg < 2; ++gg) {     // frag c' = 2n + gg, from p[8gg..8gg+7]
        unsigned int x0, x1, y0, y1;
        asm("v_cvt_pk_bf16_f32 %0, %1, %2" : "=v"(x0) : "v"(p[8 * gg + 0]), "v"(p[8 * gg + 1]));
        asm("v_cvt_pk_bf16_f32 %0, %1, %2" : "=v"(x1) : "v"(p[8 * gg + 2]), "v"(p[8 * gg + 3]));
        asm("v_cvt_pk_bf16_f32 %0, %1, %2" : "=v"(y0) : "v"(p[8 * gg + 4]), "v"(p[8 * gg + 5]));
        asm("v_cvt_pk_bf16_f32 %0, %1, %2" : "=v"(y1) : "v"(p[8 * gg + 6]), "v"(p[8 * gg + 7]));
        asm("v_permlane32_swap_b32 %0, %1" : "+v"(x0), "+v"(y0));
        asm("v_permlane32_swap_b32 %0, %1" : "+v"(x1), "+v"(y1));
        U4 fu;
        fu.u[0] = x0; fu.u[1] = x1; fu.u[2] = y0; fu.u[3] = y1;
        pa[2 * n + gg] = fu.v;
      }
    }

    // ---- O += P V : B[k][d] from Vt; frag m: d = 32m + lc ----
#pragma unroll
    for (int cp = 0; cp < 4; ++cp) {
      int d0 = lc, d1 = 32 + lc;
      int sl0 = ((2 * cp + hh) ^ ((d0 ^ (d0 >> 3)) & 7)) << 3;
      int sl1 = ((2 * cp + hh) ^ ((d1 ^ (d1 >> 3)) & 7)) << 3;
      bf16x8 bv0 = *reinterpret_cast<const bf16x8*>(Vt + d0 * 64 + sl0);
      bf16x8 bv1 = *reinterpret_cast<const bf16x8*>(Vt + d1 * 64 + sl1);
      accO0 = __builtin_amdgcn_mfma_f32_32x32x16_bf16(pa[cp], bv0, accO0, 0, 0, 0);
      accO1 = __builtin_amdgcn_mfma_f32_32x32x16_bf16(pa[cp], bv1, accO1, 0, 0, 0);
    }
  } // t

  // ---- finalize: total row-sum, redistribute 1/ls to C/D rows, store ----
  float inv = 1.f / (ls + __shfl_xor(ls, 32));
  alBuf[w][lc] = inv;
  asm volatile("s_waitcnt lgkmcnt(0)" ::: "memory");
  __builtin_amdgcn_sched_barrier(0);
#pragma unroll
  for (int r = 0; r < 16; ++r) {
    int q = (r & 3) + 8 * (r >> 2) + 4 * hh;
    float iv = alBuf[w][q];
    size_t row = (size_t)(b * T + qrow0 + q) * 1024 + hd * 64;
    o[row + lc]      = f2bf(accO0[r] * iv);
    o[row + 32 + lc] = f2bf(accO1[r] * iv);
  }
}

extern "C" void kernel_launch(void* const* d_in, const int* in_sizes, int n_in,
                              void* d_out, int out_size, void* d_ws, size_t ws_size,
                              hipStream_t stream) {
  const float* x     = (const float*)d_in[0];   // [2,2048,1024]
  const float* w_qkv = (const float*)d_in[1];   // [3072,1024]
  const float* w_out = (const float*)d_in[2];   // [1024,1024]
  float* out = (float*)d_out;                   // [2,2048,1024] fp32

  unsigned short* xb    = (unsigned short*)d_ws;                  // 4096*1024
  unsigned short* wqkvb = xb    + (size_t)4096 * 1024;            // 3072*1024
  unsigned short* woutb = wqkvb + (size_t)3072 * 1024;            // 1024*1024
  unsigned short* qkv   = woutb + (size_t)1024 * 1024;            // 4096*3072
  unsigned short* attn  = qkv   + (size_t)4096 * 3072;            // 4096*1024

  cast3_kernel<<<dim3(2048), 256, 0, stream>>>(x,     4096 * 1024 / 4,
                                               w_qkv, 3072 * 1024 / 4,
                                               w_out, 1024 * 1024 / 4,
                                               xb, wqkvb, woutb);

  gemm_bt<true ><<<dim3(32, 24), 256, 0, stream>>>(xb,   wqkvb, (void*)qkv,  4096, 3072, 1024,
                                                   0.125f, 1024);
  attn_kernel  <<<dim3(512), 256, 0, stream>>>(qkv, attn);
  gemm_bt<false><<<dim3(32,  8), 256, 0, stream>>>(attn, woutb, (void*)out, 4096, 1024, 1024,
                                                   1.0f, 0);
}